// Round 9
// baseline (128.723 us; speedup 1.0000x reference)
//
#include <hip/hip_runtime.h>
#include <hip/hip_bf16.h>
#include <stdint.h>

typedef unsigned short u16;
typedef __bf16 bf16x8 __attribute__((ext_vector_type(8)));
typedef float f32x4 __attribute__((ext_vector_type(4)));

#define B_ 2
#define T_ 2048
#define C_ 1024
#define H_ 16
#define HD 64
#define M_ (B_ * T_)   // 4096
#define N3 (3 * C_)    // 3072

#define WAITV(N) asm volatile("s_waitcnt vmcnt(" #N ")" ::: "memory")

__device__ __forceinline__ float bf2f(u16 u) {
  return __uint_as_float(((unsigned int)u) << 16);
}
__device__ __forceinline__ u16 f2bf(float f) {
  unsigned int u = __float_as_uint(f);
  u += 0x7FFF + ((u >> 16) & 1);   // round-to-nearest-even (finite inputs only)
  return (u16)(u >> 16);
}
// packed f32x2 -> bf16x2 (RNE) in one instruction
__device__ __forceinline__ unsigned cvt_pk_bf16(float lo, float hi) {
  unsigned r;
  asm("v_cvt_pk_bf16_f32 %0, %1, %2" : "=v"(r) : "v"(lo), "v"(hi));
  return r;
}
// async global->LDS, 16B per lane; lds dest = uniform base + lane*16
__device__ __forceinline__ void async16(void* ldsp, const void* gp) {
  __builtin_amdgcn_global_load_lds(
      (const __attribute__((address_space(1))) unsigned int*)gp,
      (__attribute__((address_space(3))) unsigned int*)ldsp, 16, 0, 0);
}

union U16x8 { uint4 v; u16 u[8]; };

// LDS fragment read, 128B rows: off = row*128 + kbyte, XOR-swizzled (G4).
__device__ __forceinline__ bf16x8 ldsAfrag(const char* base, int row, int kbyte) {
  int off = (row * 128 + kbyte) ^ ((row & 7) << 4);
  uint4 t = *reinterpret_cast<const uint4*>(base + off);
  return __builtin_bit_cast(bf16x8, t);
}
__device__ __forceinline__ bf16x8 ldsRead(const char* p) {
  uint4 t = *reinterpret_cast<const uint4*>(p);
  return __builtin_bit_cast(bf16x8, t);
}

// ---------------- f32 -> bf16 convert ----------------
__global__ void cvt_bf16(const float* __restrict__ src, u16* __restrict__ dst, int n4) {
  int i = blockIdx.x * blockDim.x + threadIdx.x;
  int stride = gridDim.x * blockDim.x;
  for (; i < n4; i += stride) {
    float4 v = reinterpret_cast<const float4*>(src)[i];
    uint2 o;
    o.x = (unsigned)f2bf(v.x) | ((unsigned)f2bf(v.y) << 16);
    o.y = (unsigned)f2bf(v.z) | ((unsigned)f2bf(v.w) << 16);
    reinterpret_cast<uint2*>(dst)[i] = o;
  }
}

// ---------------- RoPE cos/sin tables [T][32] f32 ----------------
__global__ void rope_tables_kernel(float* __restrict__ cosT, float* __restrict__ sinT) {
  int t = blockIdx.x;
  int i = threadIdx.x;  // 0..31
  float inv = powf(10000.0f, -(float)i * (1.0f / 32.0f));
  float f = (float)t * inv;
  cosT[t * 32 + i] = cosf(f);
  sinT[t * 32 + i] = sinf(f);
}

// ---------------- bf16 GEMM, both operands K-major (B^T input) ----------------
// staging via global_load_lds width-16, m97 2-barrier structure; source chunk
// pre-swizzled so linear LDS dest matches XOR'd reads.
template <bool OUT_F32>
__global__ __launch_bounds__(256) void gemm_bt(const u16* __restrict__ A,
                                               const u16* __restrict__ Bw,
                                               void* __restrict__ Cout,
                                               int M, int N, int K) {
  __shared__ uint4 ldsbuf[2048];  // 32KB: As 16KB + Bs 16KB
  char* As = (char*)ldsbuf;
  char* Bs = (char*)ldsbuf + 16384;
  const int tid = threadIdx.x;
  const int lane = tid & 63;
  const int wv = tid >> 6;
  const int wr = wv >> 1, wc = wv & 1;
  const int lrow = lane & 15, lgrp = lane >> 4;
  const long m0 = (long)blockIdx.x * 128, n0 = (long)blockIdx.y * 128;
  const int srow_l = lane >> 3;                      // row within 8-row segment
  const int csrc = ((lane & 7) ^ (lane >> 3)) * 8;   // pre-swizzled source chunk
  f32x4 acc[4][4] = {};
  for (int k0 = 0; k0 < K; k0 += 64) {
    __syncthreads();
#pragma unroll
    for (int p = 0; p < 4; ++p) {
      int seg = wv * 4 + p;
      int row = seg * 8 + srow_l;
      async16(As + seg * 1024, A + (size_t)(m0 + row) * K + k0 + csrc);
      async16(Bs + seg * 1024, Bw + (size_t)(n0 + row) * K + k0 + csrc);
    }
    __syncthreads();  // drains vmcnt (compiler emits vmcnt(0) before barrier)
#pragma unroll
    for (int ks = 0; ks < 2; ++ks) {
      bf16x8 af[4], bfr[4];
#pragma unroll
      for (int i = 0; i < 4; ++i) {
        af[i]  = ldsAfrag(As, wr * 64 + i * 16 + lrow, ks * 64 + lgrp * 16);
        bfr[i] = ldsAfrag(Bs, wc * 64 + i * 16 + lrow, ks * 64 + lgrp * 16);
      }
#pragma unroll
      for (int i = 0; i < 4; ++i)
#pragma unroll
        for (int j = 0; j < 4; ++j)
          acc[i][j] = __builtin_amdgcn_mfma_f32_16x16x32_bf16(af[i], bfr[j], acc[i][j], 0, 0, 0);
    }
  }
#pragma unroll
  for (int i = 0; i < 4; ++i)
#pragma unroll
    for (int j = 0; j < 4; ++j) {
      long r0 = m0 + wr * 64 + i * 16 + lgrp * 4;
      long c  = n0 + wc * 64 + j * 16 + lrow;
#pragma unroll
      for (int r = 0; r < 4; ++r) {
        float v = acc[i][j][r];
        if (OUT_F32)
          ((float*)Cout)[(r0 + r) * N + c] = v;
        else
          ((u16*)Cout)[(r0 + r) * N + c] = f2bf(v);
      }
    }
}

// ---------------- RoPE apply + reshape; Q pre-scaled by 0.125*log2(e) ----------
__global__ __launch_bounds__(256) void rope_reshape(const u16* __restrict__ qkv,
                                                    const float* __restrict__ cosT,
                                                    const float* __restrict__ sinT,
                                                    u16* __restrict__ Q,
                                                    u16* __restrict__ K,
                                                    u16* __restrict__ Vt) {
  __shared__ u16 Vs[64][80];
  const float SCLQ = 0.125f * 1.4426950408889634f;  // folded into Q
  const int tid = threadIdx.x;
  const int tblk = blockIdx.x, bh = blockIdx.y;
  const int b = bh >> 4, h = bh & 15;
  const int tl = tid >> 2, quar = tid & 3;
  const int t = tblk * 64 + tl;
  const u16* rowp = qkv + ((size_t)(b * T_ + t)) * N3 + h * HD;
  const int d0 = quar * 8;
  float cs[8], sn[8];
#pragma unroll
  for (int j = 0; j < 8; ++j) {
    cs[j] = cosT[t * 32 + d0 + j];
    sn[j] = sinT[t * 32 + d0 + j];
  }
#pragma unroll
  for (int part = 0; part < 2; ++part) {
    const u16* p = rowp + part * C_;
    U16x8 x1, x2, o1, o2;
    x1.v = *reinterpret_cast<const uint4*>(p + d0);
    x2.v = *reinterpret_cast<const uint4*>(p + d0 + 32);
#pragma unroll
    for (int j = 0; j < 8; ++j) {
      float a = bf2f(x1.u[j]), c2 = bf2f(x2.u[j]);
      float f1 = a * cs[j] - c2 * sn[j];
      float f2 = c2 * cs[j] + a * sn[j];
      if (part == 0) { f1 *= SCLQ; f2 *= SCLQ; }
      o1.u[j] = f2bf(f1);
      o2.u[j] = f2bf(f2);
    }
    u16* dst = (part ? K : Q) + ((size_t)bh * T_ + t) * HD;
    *reinterpret_cast<uint4*>(dst + d0) = o1.v;
    *reinterpret_cast<uint4*>(dst + d0 + 32) = o2.v;
  }
  const u16* pv = rowp + 2 * C_;
#pragma unroll
  for (int c = 0; c < 2; ++c) {
    int d = quar * 16 + c * 8;
    *reinterpret_cast<uint4*>(&Vs[tl][d]) = *reinterpret_cast<const uint4*>(pv + d);
  }
  __syncthreads();
  const int d = tid >> 2, tq = tid & 3;
  U16x8 a, bv;
#pragma unroll
  for (int j = 0; j < 8; ++j) a.u[j] = Vs[tq * 16 + j][d];
#pragma unroll
  for (int j = 0; j < 8; ++j) bv.u[j] = Vs[tq * 16 + 8 + j][d];
  u16* dstv = Vt + ((size_t)bh * HD + d) * T_ + tblk * 64 + tq * 16;
  *reinterpret_cast<uint4*>(dstv) = a.v;
  *reinterpret_cast<uint4*>(dstv + 8) = bv.v;
}

// ---------------- causal flash attention v9 ----------------
// T3/T4: KBLK=64, 4-slot LDS ring (16KB tiles), 3-deep async prefetch via
// global_load_lds, raw s_barrier + COUNTED s_waitcnt vmcnt(N) (never a full
// drain in steady state). N = 4 * (#stages newer than the tile needed next):
// 8 steady / 4 at nu-3 / 0 at nu-2. sched_barrier(0) fences after each barrier.
__global__ __launch_bounds__(256) void attn_fwd9(const u16* __restrict__ Q,
                                                 const u16* __restrict__ K,
                                                 const u16* __restrict__ Vt,
                                                 u16* __restrict__ O) {
  // 4 ring slots x (K 8KB + V 8KB) + 4 waves x 2KB P = 72KB -> 2 blocks/CU
  __shared__ uint4 lds4[4608];
  char* ldsb = (char*)lds4;
  const int tid = threadIdx.x;
  const int lane = tid & 63, wv = tid >> 6;
  const int lrow = lane & 15, lgrp = lane >> 4;
  const int bh = blockIdx.y;
  const int b = bh >> 4, h = bh & 15;
  const u16* Qh = Q + (size_t)bh * T_ * HD;
  const u16* Kh = K + (size_t)bh * T_ * HD;
  const u16* Vh = Vt + (size_t)bh * HD * T_;

  // staging: per thread 2 K-chunks + 2 V-chunks per 64x64 tile
  const int srow_l = lane >> 3;                      // row within 8-row group
  const int csrc = ((lane & 7) ^ (lane >> 3)) * 8;   // pre-swizzled source chunk

  auto stage = [&](int slot, int kt) {
    char* Kd = ldsb + (slot << 14);
    char* Vd = Kd + 8192;
    const u16* Kg = Kh + (size_t)(kt * 64) * HD;
    const u16* Vg = Vh + kt * 64;
#pragma unroll
    for (int seg = 0; seg < 2; ++seg) {
      int row = wv * 16 + seg * 8 + srow_l;
      async16(Kd + wv * 2048 + seg * 1024, Kg + (size_t)row * HD + csrc);
      async16(Vd + wv * 2048 + seg * 1024, Vg + (size_t)row * T_ + csrc);
    }
  };

  // hoisted swizzled bases (swz bits 4-6; strides 128B)
  const int swz = (lrow & 7) << 4;
  const int krA = lrow * 128 + ((lgrp * 16) ^ swz);
  const int krB = lrow * 128 + ((64 + lgrp * 16) ^ swz);
  const int vrA = 8192 + krA;
  const int vrB = 8192 + krB;
  char* PsW = ldsb + 65536 + wv * 2048 + lrow * 128;
  char* pw0 = PsW + ((0 * 32 + lgrp * 8) ^ swz);
  char* pw1 = PsW + ((1 * 32 + lgrp * 8) ^ swz);
  char* pw2 = PsW + ((2 * 32 + lgrp * 8) ^ swz);
  char* pw3 = PsW + ((3 * 32 + lgrp * 8) ^ swz);
  const char* paA = PsW + ((lgrp * 16) ^ swz);
  const char* paB = PsW + ((64 + lgrp * 16) ^ swz);

  uint4 ones4;
  ones4.x = ones4.y = ones4.z = ones4.w = 0x3F803F80u;
  const bf16x8 ones8 = __builtin_bit_cast(bf16x8, ones4);

#pragma unroll
  for (int uu = 0; uu < 2; ++uu) {
    const int unit = uu ? (31 - (int)blockIdx.x) : (int)blockIdx.x;
    const int qs = unit * 64;
    const int q_glob = qs + wv * 16 + lrow;
    const int nu = unit + 1;  // 64-key tiles needed

    bf16x8 qf[2];
#pragma unroll
    for (int ks = 0; ks < 2; ++ks) {
      uint4 t4 = *reinterpret_cast<const uint4*>(
          Qh + (size_t)(qs + wv * 16 + lrow) * HD + ks * 32 + lgrp * 8);
      qf[ks] = __builtin_bit_cast(bf16x8, t4);
    }
    f32x4 o[4] = {};
    f32x4 lacc = {};

    // prologue: fill up to 3 ring slots, drain, publish
    {
      const int pre = nu < 3 ? nu : 3;
      for (int i = 0; i < pre; ++i) stage(i, i);
      WAITV(0);
      __builtin_amdgcn_s_barrier();
      __builtin_amdgcn_sched_barrier(0);
    }

    for (int kt = 0; kt < nu; ++kt) {
      if (kt + 3 < nu) stage((kt + 3) & 3, kt + 3);
      const char* buf = ldsb + ((kt & 3) << 14);
      const char* KbA = buf + krA;
      const char* KbB = buf + krB;
      const char* VbA = buf + vrA;
      const char* VbB = buf + vrB;

      // S^T = K Q^T : lane owns 16 keys of q-row (lane&15); S pre-scaled (exp2)
      f32x4 s[4] = {};
      __builtin_amdgcn_s_setprio(1);
#pragma unroll
      for (int n = 0; n < 4; ++n)
        s[n] = __builtin_amdgcn_mfma_f32_16x16x32_bf16(ldsRead(KbA + n * 2048), qf[0], s[n], 0, 0, 0);
#pragma unroll
      for (int n = 0; n < 4; ++n)
        s[n] = __builtin_amdgcn_mfma_f32_16x16x32_bf16(ldsRead(KbB + n * 2048), qf[1], s[n], 0, 0, 0);
      __builtin_amdgcn_s_setprio(0);

      // P = 2^S (causal mask on the diagonal tile only)
      if (kt == nu - 1) {
#pragma unroll
        for (int n = 0; n < 4; ++n)
#pragma unroll
          for (int r = 0; r < 4; ++r) {
            int kg = kt * 64 + n * 16 + lgrp * 4 + r;
            float v = (kg <= q_glob) ? s[n][r] : -__builtin_inff();
            s[n][r] = exp2f(v);
          }
      } else {
#pragma unroll
        for (int n = 0; n < 4; ++n)
#pragma unroll
          for (int r = 0; r < 4; ++r) s[n][r] = exp2f(s[n][r]);
      }

      // P -> per-wave LDS (4 b64 writes at hoisted bases)
      {
        uint2 w0, w1, w2, w3;
        w0.x = cvt_pk_bf16(s[0][0], s[0][1]); w0.y = cvt_pk_bf16(s[0][2], s[0][3]);
        w1.x = cvt_pk_bf16(s[1][0], s[1][1]); w1.y = cvt_pk_bf16(s[1][2], s[1][3]);
        w2.x = cvt_pk_bf16(s[2][0], s[2][1]); w2.y = cvt_pk_bf16(s[2][2], s[2][3]);
        w3.x = cvt_pk_bf16(s[3][0], s[3][1]); w3.y = cvt_pk_bf16(s[3][2], s[3][3]);
        *reinterpret_cast<uint2*>(pw0) = w0;
        *reinterpret_cast<uint2*>(pw1) = w1;
        *reinterpret_cast<uint2*>(pw2) = w2;
        *reinterpret_cast<uint2*>(pw3) = w3;
      }

      // O += P * V ; l += P * ones
      __builtin_amdgcn_s_setprio(1);
#pragma unroll
      for (int ks = 0; ks < 2; ++ks) {
        bf16x8 pa = ldsRead(ks ? paB : paA);
        lacc = __builtin_amdgcn_mfma_f32_16x16x32_bf16(pa, ones8, lacc, 0, 0, 0);
        const char* vbb = ks ? VbB : VbA;
#pragma unroll
        for (int dn = 0; dn < 4; ++dn) {
          bf16x8 bv = ldsRead(vbb + dn * 2048);
          o[dn] = __builtin_amdgcn_mfma_f32_16x16x32_bf16(pa, bv, o[dn], 0, 0, 0);
        }
      }
      __builtin_amdgcn_s_setprio(0);

      // counted wait: tile kt+1 must be landed; newer stages may stay in flight
      if (kt + 4 <= nu)      WAITV(8);
      else if (kt + 3 == nu) WAITV(4);
      else                   WAITV(0);
      __builtin_amdgcn_s_barrier();
      __builtin_amdgcn_sched_barrier(0);
    }

    // epilogue: lacc[r] is the row sum for q-row lgrp*4+r (same layout as o)
#pragma unroll
    for (int r = 0; r < 4; ++r) {
      float inv = 1.0f / lacc[r];
      int t = qs + wv * 16 + lgrp * 4 + r;
#pragma unroll
      for (int dn = 0; dn < 4; ++dn) {
        int c = h * HD + dn * 16 + lrow;
        O[((size_t)(b * T_ + t)) * C_ + c] = f2bf(o[dn][r] * inv);
      }
    }
  }
}

// ---------------- launch ----------------
extern "C" void kernel_launch(void* const* d_in, const int* in_sizes, int n_in,
                              void* d_out, int out_size, void* d_ws, size_t ws_size,
                              hipStream_t stream) {
  const float* x  = (const float*)d_in[0];
  const float* wa = (const float*)d_in[1];
  const float* wp = (const float*)d_in[2];
  float* out = (float*)d_out;
  char* ws = (char*)d_ws;
  size_t off = 0;
  auto alloc = [&](size_t bytes) {
    char* p = ws + off;
    off += (bytes + 255) & ~(size_t)255;
    return p;
  };
  u16* xb   = (u16*)alloc((size_t)M_ * C_ * 2);
  u16* wab  = (u16*)alloc((size_t)N3 * C_ * 2);
  u16* wpb  = (u16*)alloc((size_t)C_ * C_ * 2);
  u16* qkvb = (u16*)alloc((size_t)M_ * N3 * 2);
  u16* Qb   = (u16*)alloc((size_t)B_ * H_ * T_ * HD * 2);
  u16* Kb   = (u16*)alloc((size_t)B_ * H_ * T_ * HD * 2);
  u16* Vtb  = (u16*)alloc((size_t)B_ * H_ * T_ * HD * 2);
  u16* Ob   = (u16*)alloc((size_t)M_ * C_ * 2);
  float* cosT = (float*)alloc((size_t)T_ * 32 * 4);
  float* sinT = (float*)alloc((size_t)T_ * 32 * 4);
  (void)in_sizes; (void)n_in; (void)out_size; (void)ws_size;

  cvt_bf16<<<1024, 256, 0, stream>>>(x, xb, M_ * C_ / 4);
  cvt_bf16<<<1024, 256, 0, stream>>>(wa, wab, N3 * C_ / 4);
  cvt_bf16<<<512, 256, 0, stream>>>(wp, wpb, C_ * C_ / 4);
  rope_tables_kernel<<<T_, 32, 0, stream>>>(cosT, sinT);
  gemm_bt<false><<<dim3(M_ / 128, N3 / 128), 256, 0, stream>>>(xb, wab, qkvb, M_, N3, C_);
  rope_reshape<<<dim3(T_ / 64, B_ * H_), 256, 0, stream>>>(qkvb, cosT, sinT, Qb, Kb, Vtb);
  attn_fwd9<<<dim3(16, B_ * H_), 256, 0, stream>>>(Qb, Kb, Vtb, Ob);
  gemm_bt<true><<<dim3(M_ / 128, C_ / 128), 256, 0, stream>>>(Ob, wpb, out, M_, C_, C_);
}